// Round 5
// baseline (72.440 us; speedup 1.0000x reference)
//
#include <hip/hip_runtime.h>

// BEV orthographic 3D Gaussian splatting, B=2, N=1024, D=32, H=W=200.
// Structure = R4 (71.7us) with 2-tile prepass amortization:
//  - Grid (13,25,2), 650 blocks. Block bx renders tiles tx=bx and tx=bx+13
//    (center+edge pairing; bx=12 renders only tile 12). Tile coverage exact.
//  - Prepass computes DERIVED per-gaussian params (u,v,A,B,C,pl,o,qmax*lmax)
//    once per wave-segment into registers; both tiles reuse them. Per-tile
//    recompute is just the 8-VALU bbox test.
//  - Invalid gaussians (op<=0.05 or det<=0) encoded u=v=1e30, qlm=0 ->
//    bbox always false (dmx^2 = inf > 0).
//  - Ballot-bit-scan walk, eps-stop (segment-local T, 128-chunk boundary),
//    cross-wave combine, stores: byte-identical math to R4.
//  - One extra barrier per second tile guards simg/sT reuse.
// Output: [bev (2,32,200,200) | mean_count scalar].

#define HH 200
#define WW 200
#define DD 32
#define NG 1024
#define BB 2
#define OUT_IMG (BB*DD*HH*WW)   // 2560000
#define NW 4                    // waves per block = gaussian segments
#define SEGG (NG/NW)            // 256 gaussians per segment
#define NGRP (SEGG/64)          // 4 groups of 64
#define TILES_X 25
#define GRID_X 13

__device__ __forceinline__ float rlane(float x, int l) {
    return __uint_as_float(__builtin_amdgcn_readlane(__float_as_uint(x), l));
}

__global__ __launch_bounds__(64*NW, 4) void render_kernel(
    const float* __restrict__ feats,   // (B, NG, DD)
    const float* __restrict__ means,   // (B, NG, 3)
    const float* __restrict__ cov,     // (B, NG, 6)
    const float* __restrict__ opac,    // (B, NG)
    float* __restrict__ out)
{
    __shared__ float4 simg[NW][64][8];   // swizzled ch4 slot = (c4+px)&7
    __shared__ float sT[NW][64];
    __shared__ float wsum[NW];

    const int b    = blockIdx.z;
    const int tid  = threadIdx.x;
    const int lane = tid & 63;
    const int wid  = tid >> 6;
    const float pyf = (float)(blockIdx.y*8 + (lane >> 3));
    const float cy  = blockIdx.y*8 + 3.5f;

    const float* __restrict__ featsB = feats + (size_t)b * NG * DD;
    const int gB = b * NG;

    // ---- prepass: derived params for this wave's 256-gaussian segment (regs)
    float u_[NGRP], v_[NGRP], A_[NGRP], B_[NGRP], C_[NGRP],
          pl_[NGRP], o_[NGRP], q_[NGRP];
#pragma unroll
    for (int k = 0; k < NGRP; ++k) {
        const int g = gB + wid*SEGG + k*64 + lane;
        const float o   = opac[g];
        const float2 c01 = *(const float2*)(cov + (size_t)g*6);  // 8B-aligned
        const float c3  = cov[(size_t)g*6 + 3];
        const float m0  = means[(size_t)g*3 + 0];
        const float m1  = means[(size_t)g*3 + 1];
        const float av = 4.f*c3    + 0.3f;       // image-x variance
        const float cv = 4.f*c01.x + 0.3f;       // image-y variance
        const float bv = 4.f*c01.y;
        const float det = av*cv - bv*bv;
        float u=1e30f, v=1e30f, A=0.f, Bc=0.f, Cc=0.f, pl=0.f, qlm=0.f;
        if (o > 0.05f && det > 0.f) {
            u = -2.f*m1 + 100.f;
            v = -2.f*m0 + 100.f;
            pl = -__logf(255.f*o);               // power floor for alpha>=1/255
            const float htr = 0.5f*(av+cv), hdf = 0.5f*(av-cv);
            const float lmax = htr + sqrtf(hdf*hdf + bv*bv);  // lmax(cov2D)
            qlm = -2.f*pl*lmax;                  // qmax*lmax (radius^2 bound)
            const float inv = 1.f/det;
            A = cv*inv; Bc = bv*inv; Cc = av*inv;
        }
        u_[k]=u; v_[k]=v; A_[k]=A; B_[k]=Bc; C_[k]=Cc;
        pl_[k]=pl; o_[k]=o; q_[k]=qlm;
    }

    // ---- fused mean_count (one block), before tile loop
    if (blockIdx.x == 0 && blockIdx.y == 0 && b == 0) {
        float s = 0.f;
        for (int i = tid; i < BB*NG; i += 64*NW)
            s += (opac[i] > 0.05f) ? 1.f : 0.f;
#pragma unroll
        for (int off = 32; off > 0; off >>= 1)
            s += __shfl_down(s, off, 64);
        if (lane == 0) wsum[wid] = s;
        __syncthreads();
        if (tid == 0)
            out[OUT_IMG] = (wsum[0]+wsum[1]+wsum[2]+wsum[3]) * (1.f/(float)BB);
    }

    for (int t = 0; t < 2; ++t) {
        const int tx = blockIdx.x + t*GRID_X;
        if (tx >= TILES_X) break;                // block-uniform
        const float pxf = (float)(tx*8 + (lane & 7));
        const float cx  = tx*8 + 3.5f;

        float4 acc[8];
#pragma unroll
        for (int j = 0; j < 8; ++j) acc[j] = make_float4(0.f,0.f,0.f,0.f);
        float T = 1.f, P = 1.f;
        bool skip = false;

#pragma unroll
        for (int k = 0; k < NGRP; ++k) {
            const int gbase = wid*SEGG + k*64;
            const float dmx = fmaxf(fabsf(u_[k] - cx), fabsf(v_[k] - cy)) - 4.f;
            const bool flag = (dmx <= 0.f) || (dmx*dmx <= q_[k]);
            unsigned long long mm = __ballot(flag);   // bit order == index order
            if (!skip) {
                while (mm) {
                    const int i = (int)__builtin_ctzll(mm);
                    mm &= mm - 1ull;
                    const float ui  = rlane(u_[k],  i);
                    const float vi  = rlane(v_[k],  i);
                    const float Ai  = rlane(A_[k],  i);
                    const float Bi  = rlane(B_[k],  i);
                    const float Ci  = rlane(C_[k],  i);
                    const float oi  = rlane(o_[k],  i);
                    const float pli = rlane(pl_[k], i);
                    const float dx = ui - pxf;
                    const float dy = vi - pyf;
                    const float pw = fmaf(Bi, dx*dy,
                                          -0.5f*(Ai*dx*dx + Ci*dy*dy));
                    if (pw > 0.f) continue;                 // reference mask
                    if (pw < pli - 1e-3f) continue;         // provably alpha<1/255
                    const float alpha = fminf(0.99f, oi * __expf(pw));
                    if (alpha < (1.f/255.f)) continue;      // exact check
                    const float om = 1.f - alpha;
                    const float tp = T * P;
                    if (tp * om < 1e-4f) { skip = true; break; }  // eps-stop
                    const float w = alpha * tp;
                    const float4* __restrict__ col =        // wave-uniform addr
                        (const float4*)(featsB + (size_t)(gbase + i) * DD);
#pragma unroll
                    for (int j = 0; j < 8; ++j) {
                        const float4 c4 = col[j];
                        acc[j].x = fmaf(w, c4.x, acc[j].x);
                        acc[j].y = fmaf(w, c4.y, acc[j].y);
                        acc[j].z = fmaf(w, c4.z, acc[j].z);
                        acc[j].w = fmaf(w, c4.w, acc[j].w);
                    }
                    P *= om;
                }
            }
            if (k & 1) { T *= P; P = 1.f; skip = false; }   // 128-chunk boundary
        }

        // ---- cross-wave combine: img = sum_s prefixT_s * img_s
        if (t) __syncthreads();                  // guard simg/sT reuse
        sT[wid][lane] = T;
#pragma unroll
        for (int j = 0; j < 8; ++j)
            simg[wid][lane][(j + lane) & 7] = acc[j];        // bank-swizzled
        __syncthreads();

        {
            const int p   = tid & 63;                        // pixel in tile
            const int grp = tid >> 6;                        // channel-quad pair
            const float t0 = sT[0][p], t1 = sT[1][p], t2 = sT[2][p];
            const float pf1 = t0, pf2 = t0*t1, pf3 = pf2*t2;
            const int ppx = tx*8 + (p & 7);
            const int ppy = blockIdx.y*8 + (p >> 3);
            const size_t base = (size_t)b * DD * (HH*WW)
                              + (size_t)ppy * WW + ppx;
#pragma unroll
            for (int q = 0; q < 2; ++q) {
                const int c4 = grp*2 + q;
                const int slot = (c4 + p) & 7;
                const float4 r0 = simg[0][p][slot];
                const float4 r1 = simg[1][p][slot];
                const float4 r2 = simg[2][p][slot];
                const float4 r3 = simg[3][p][slot];
                float4 ov;
                ov.x = fmaf(pf3, r3.x, fmaf(pf2, r2.x, fmaf(pf1, r1.x, r0.x)));
                ov.y = fmaf(pf3, r3.y, fmaf(pf2, r2.y, fmaf(pf1, r1.y, r0.y)));
                ov.z = fmaf(pf3, r3.z, fmaf(pf2, r2.z, fmaf(pf1, r1.z, r0.z)));
                ov.w = fmaf(pf3, r3.w, fmaf(pf2, r2.w, fmaf(pf1, r1.w, r0.w)));
                out[base + (size_t)(c4*4+0)*(HH*WW)] = ov.x;
                out[base + (size_t)(c4*4+1)*(HH*WW)] = ov.y;
                out[base + (size_t)(c4*4+2)*(HH*WW)] = ov.z;
                out[base + (size_t)(c4*4+3)*(HH*WW)] = ov.w;
            }
        }
    }
}

extern "C" void kernel_launch(void* const* d_in, const int* in_sizes, int n_in,
                              void* d_out, int out_size, void* d_ws, size_t ws_size,
                              hipStream_t stream) {
    const float* feats = (const float*)d_in[0];  // features (B,N,D)
    const float* means = (const float*)d_in[1];  // means3D  (B,N,3)
    const float* cvr   = (const float*)d_in[2];  // cov3D    (B,N,6)
    const float* opc   = (const float*)d_in[3];  // opacities(B,N,1)
    float* out = (float*)d_out;

    render_kernel<<<dim3(GRID_X, HH/8, BB), dim3(64*NW), 0, stream>>>(
        feats, means, cvr, opc, out);
}

// Round 6
// 71.299 us; speedup vs baseline: 1.0160x; 1.0160x over previous
//
#include <hip/hip_runtime.h>

// BEV orthographic 3D Gaussian splatting, B=2, N=1024, D=32, H=W=200.
// == R4 revert (best measured: 71.68us). ==
// Structure: one launch, 25x25x2 blocks, 8x8 tile, 4 waves/block each owning
// a 256-gaussian segment (2 ref 128-chunks), ballot-bit-scan + readlane
// broadcast, no barriers in the main loop, cross-wave combine via the
// associative operator (img1,T1)o(img2,T2) = (img1 + T1*img2, T1*T2).
//  - All 4 groups' prepass loads (opac/cov/means, 20 VMEM) issued up front
//    into registers via static unroll -> 1 exposed latency window.
//  - bbox cull uses squared compare dmx^2 <= qmax*lmax (no serial sqrt in
//    the dependent chain; conservative bound, exact per-pixel tests follow).
// Eps-stop: segment-local T with 128-chunk boundary reset -> under-triggers
// vs reference (strict superset of included set); bounded extra weight,
// verified at absmax 0.00390625 across R1-R5.
// R5 post-mortem: 2-tile prepass amortization was neutral-to-negative ->
// cross-block prepass redundancy is not a live bottleneck; kernel slice is
// ~5-10us of a ~71.7us iteration dominated by harness fill (41us) + resets.
// Output: [bev (2,32,200,200) | mean_count scalar].

#define HH 200
#define WW 200
#define DD 32
#define NG 1024
#define BB 2
#define OUT_IMG (BB*DD*HH*WW)   // 2560000
#define NW 4                    // waves per block = gaussian segments
#define SEGG (NG/NW)            // 256 gaussians per segment
#define NGRP (SEGG/64)          // 4 groups of 64

__device__ __forceinline__ float rlane(float x, int l) {
    return __uint_as_float(__builtin_amdgcn_readlane(__float_as_uint(x), l));
}

__global__ __launch_bounds__(64*NW, 4) void render_kernel(
    const float* __restrict__ feats,   // (B, NG, DD)
    const float* __restrict__ means,   // (B, NG, 3)
    const float* __restrict__ cov,     // (B, NG, 6)
    const float* __restrict__ opac,    // (B, NG)
    float* __restrict__ out)
{
    __shared__ float4 simg[NW][64][8];   // swizzled ch4 slot = (c4+px)&7
    __shared__ float sT[NW][64];
    __shared__ float wsum[NW];

    const int b    = blockIdx.z;
    const int tid  = threadIdx.x;
    const int lane = tid & 63;
    const int wid  = tid >> 6;
    const float pxf = (float)(blockIdx.x*8 + (lane & 7));
    const float pyf = (float)(blockIdx.y*8 + (lane >> 3));
    const float cx  = blockIdx.x*8 + 3.5f;
    const float cy  = blockIdx.y*8 + 3.5f;

    const float* __restrict__ featsB = feats + (size_t)b * NG * DD;
    const int gB = b * NG;

    // ---- upfront prepass loads for all 4 groups (independent, issue together)
    float o_[NGRP], c0_[NGRP], c1_[NGRP], c3_[NGRP], m0_[NGRP], m1_[NGRP];
#pragma unroll
    for (int k = 0; k < NGRP; ++k) {
        const int g = gB + wid*SEGG + k*64 + lane;
        o_[k] = opac[g];
        const float2 c01 = *(const float2*)(cov + (size_t)g*6);  // 8B-aligned
        c0_[k] = c01.x; c1_[k] = c01.y;
        c3_[k] = cov[(size_t)g*6 + 3];
        m0_[k] = means[(size_t)g*3 + 0];
        m1_[k] = means[(size_t)g*3 + 1];
    }

    float4 acc[8];
#pragma unroll
    for (int j = 0; j < 8; ++j) acc[j] = make_float4(0.f,0.f,0.f,0.f);
    float T = 1.f, P = 1.f;
    bool skip = false;

#pragma unroll
    for (int k = 0; k < NGRP; ++k) {
        const int gbase = wid*SEGG + k*64;       // segment-local base index
        const float o  = o_[k];
        const float av = 4.f*c3_[k] + 0.3f;      // image-x variance
        const float cv = 4.f*c0_[k] + 0.3f;      // image-y variance
        const float bv = 4.f*c1_[k];
        const float det = av*cv - bv*bv;
        bool flag = false;
        float u=0.f, v=0.f, A=0.f, Bc=0.f, Cc=0.f, pl=0.f;
        if (o > 0.05f && det > 0.f) {
            u = -2.f*m1_[k] + 100.f;
            v = -2.f*m0_[k] + 100.f;
            pl = -__logf(255.f*o);               // power floor for alpha>=1/255
            const float qmax = -2.f*pl;          // >0 since o>0.05
            const float htr = 0.5f*(av+cv), hdf = 0.5f*(av-cv);
            const float lmax = htr + sqrtf(hdf*hdf + bv*bv);  // lmax(cov2D)
            // old: max(|du|,|dv|) <= 3.5 + (sqrt(qmax*lmax)+0.5)
            const float dmx = fmaxf(fabsf(u - cx), fabsf(v - cy)) - 4.0f;
            if (dmx <= 0.f || dmx*dmx <= qmax*lmax) {
                const float inv = 1.f/det;       // exact division, rare path
                A = cv*inv; Bc = bv*inv; Cc = av*inv;
                flag = true;
            }
        }
        unsigned long long mm = __ballot(flag);  // bit order == index order
        if (!skip) {
            while (mm) {
                const int i = (int)__builtin_ctzll(mm);
                mm &= mm - 1ull;
                const float ui  = rlane(u,  i);
                const float vi  = rlane(v,  i);
                const float Ai  = rlane(A,  i);
                const float Bi  = rlane(Bc, i);
                const float Ci  = rlane(Cc, i);
                const float oi  = rlane(o,  i);
                const float pli = rlane(pl, i);
                const float dx = ui - pxf;
                const float dy = vi - pyf;
                const float pw = fmaf(Bi, dx*dy, -0.5f*(Ai*dx*dx + Ci*dy*dy));
                if (pw > 0.f) continue;                    // reference mask
                if (pw < pli - 1e-3f) continue;            // provably alpha<1/255
                const float alpha = fminf(0.99f, oi * __expf(pw));
                if (alpha < (1.f/255.f)) continue;         // exact check
                const float om = 1.f - alpha;
                const float tp = T * P;
                if (tp * om < 1e-4f) { skip = true; break; }  // chunk eps-stop
                const float w = alpha * tp;
                const float4* __restrict__ col =           // wave-uniform addr
                    (const float4*)(featsB + (size_t)(gbase + i) * DD);
#pragma unroll
                for (int j = 0; j < 8; ++j) {
                    const float4 c4 = col[j];
                    acc[j].x = fmaf(w, c4.x, acc[j].x);
                    acc[j].y = fmaf(w, c4.y, acc[j].y);
                    acc[j].z = fmaf(w, c4.z, acc[j].z);
                    acc[j].w = fmaf(w, c4.w, acc[j].w);
                }
                P *= om;
            }
        }
        if (k & 1) { T *= P; P = 1.f; skip = false; }   // 128-chunk boundary
    }

    // ---- cross-wave combine: img = sum_s prefixT_s * img_s
    sT[wid][lane] = T;
#pragma unroll
    for (int j = 0; j < 8; ++j)
        simg[wid][lane][(j + lane) & 7] = acc[j];        // bank-swizzled
    __syncthreads();

    {
        const int p   = tid & 63;                        // pixel within tile
        const int grp = tid >> 6;                        // channel-quad pair
        const float t0 = sT[0][p], t1 = sT[1][p], t2 = sT[2][p];
        const float pf1 = t0, pf2 = t0*t1, pf3 = pf2*t2;
        const int ppx = blockIdx.x*8 + (p & 7);
        const int ppy = blockIdx.y*8 + (p >> 3);
        const size_t base = (size_t)b * DD * (HH*WW) + (size_t)ppy * WW + ppx;
#pragma unroll
        for (int q = 0; q < 2; ++q) {
            const int c4 = grp*2 + q;
            const int slot = (c4 + p) & 7;
            const float4 r0 = simg[0][p][slot];
            const float4 r1 = simg[1][p][slot];
            const float4 r2 = simg[2][p][slot];
            const float4 r3 = simg[3][p][slot];
            float4 ov;
            ov.x = fmaf(pf3, r3.x, fmaf(pf2, r2.x, fmaf(pf1, r1.x, r0.x)));
            ov.y = fmaf(pf3, r3.y, fmaf(pf2, r2.y, fmaf(pf1, r1.y, r0.y)));
            ov.z = fmaf(pf3, r3.z, fmaf(pf2, r2.z, fmaf(pf1, r1.z, r0.z)));
            ov.w = fmaf(pf3, r3.w, fmaf(pf2, r2.w, fmaf(pf1, r1.w, r0.w)));
            out[base + (size_t)(c4*4+0)*(HH*WW)] = ov.x;
            out[base + (size_t)(c4*4+1)*(HH*WW)] = ov.y;
            out[base + (size_t)(c4*4+2)*(HH*WW)] = ov.z;
            out[base + (size_t)(c4*4+3)*(HH*WW)] = ov.w;
        }
    }

    // ---- fused mean_count (one block)
    if (blockIdx.x == 0 && blockIdx.y == 0 && b == 0) {
        float s = 0.f;
        for (int i = tid; i < BB*NG; i += 64*NW)
            s += (opac[i] > 0.05f) ? 1.f : 0.f;
#pragma unroll
        for (int off = 32; off > 0; off >>= 1)
            s += __shfl_down(s, off, 64);
        if (lane == 0) wsum[wid] = s;
        __syncthreads();
        if (tid == 0)
            out[OUT_IMG] = (wsum[0]+wsum[1]+wsum[2]+wsum[3]) * (1.f/(float)BB);
    }
}

extern "C" void kernel_launch(void* const* d_in, const int* in_sizes, int n_in,
                              void* d_out, int out_size, void* d_ws, size_t ws_size,
                              hipStream_t stream) {
    const float* feats = (const float*)d_in[0];  // features (B,N,D)
    const float* means = (const float*)d_in[1];  // means3D  (B,N,3)
    const float* cvr   = (const float*)d_in[2];  // cov3D    (B,N,6)
    const float* opc   = (const float*)d_in[3];  // opacities(B,N,1)
    float* out = (float*)d_out;

    render_kernel<<<dim3(WW/8, HH/8, BB), dim3(64*NW), 0, stream>>>(
        feats, means, cvr, opc, out);
}